// Round 4
// baseline (173.761 us; speedup 1.0000x reference)
//
#include <hip/hip_runtime.h>
#include <hip/hip_bf16.h>

// CIN (xDeepFM) fused 3-layer kernel for MI355X — R4: barrierless K-loop,
// W direct global->VGPR (L2-resident), no W LDS staging.
// B=1024, F0=32, D=32, H=128 per layer.
// Layer: h[b,d,h] = sum_{f,g} x0[b,f,d]*S[b,g,d]*W[f*Fk+g,h] + bias[h]
//      = sum_f x0[b,f,d] * (S(b,:,d) . W_f)[h]
// Transposed MFMA: D[m=h][n=r=(b,d)] = sum_k W_f[k,h] * S[r,k]
//   A-frag = W, loaded straight from global (packed bf16, L2-resident),
//            double-buffered in registers: next-f loads in flight while
//            current-f MFMAs run (never waits the queue to empty).
//   B-frag = S, registers, loaded once per layer from 32KB LDS state.
//   x0 scale applied post-MFMA: outacc += xs_lane * Y_f
// R1-R3 all plateaued at ~114 µs regardless of VALU/occupancy: the wall was
// the barrier-synchronized LDS-staging pipeline (72 stage barriers + 1
// ds_read_b128 per MFMA). This version has 6 barriers total and zero
// per-MFMA LDS traffic.
// Grid: 256 WGs x 512 thr = 1 WG/CU, 8 waves (mrow 0..3 h-tiles x npair 0..1
// batch-pairs); each wave: 32 h-rows x 2 batches -> 1 W-load per 2 MFMA.

typedef __attribute__((ext_vector_type(8))) short short8;
typedef __attribute__((ext_vector_type(8))) __bf16 bf16x8;
typedef __attribute__((ext_vector_type(16))) float f32x16;
typedef __attribute__((ext_vector_type(4))) unsigned short u16x4;

#define DEVINL static __device__ __forceinline__

DEVINL unsigned short f2bf_rne(float f) {
  unsigned int u = __builtin_bit_cast(unsigned int, f);
  unsigned int r = u + 0x7fffu + ((u >> 16) & 1u);
  return (unsigned short)(r >> 16);
}

// MFMA adapter: builtin may want v8i16 or v8bf16. SFINAE both.
template <typename V>
DEVINL auto mfma_32x32x16_bf16(V a, V b, f32x16 c, int)
    -> decltype(__builtin_amdgcn_mfma_f32_32x32x16_bf16(a, b, c, 0, 0, 0)) {
  return __builtin_amdgcn_mfma_f32_32x32x16_bf16(a, b, c, 0, 0, 0);
}
template <typename V>
DEVINL f32x16 mfma_32x32x16_bf16(V a, V b, f32x16 c, long) {
  return __builtin_amdgcn_mfma_f32_32x32x16_bf16(
      __builtin_bit_cast(bf16x8, a), __builtin_bit_cast(bf16x8, b), c, 0, 0, 0);
}
DEVINL f32x16 mfma_bf16(short8 a, short8 b, f32x16 c) {
  return mfma_32x32x16_bf16(a, b, c, 0);
}

// ---------------- W pack kernel (unchanged, verified R2/R3) ----------------
// Packed layout per layer: [f][kb=k>>3][h][j=k&7] bf16 (granule = 1024 u16).
__global__ void pack_w_kernel(const float* __restrict__ W0,
                              const float* __restrict__ W1,
                              const float* __restrict__ W2,
                              unsigned short* __restrict__ Wt) {
  __shared__ float tile[8][132];
  const int u = blockIdx.x;
  const float* W; int FK, f, kb, base;
  if (u < 128)      { W = W0; FK = 32;  f = u >> 2;         kb = u & 3;          base = 0; }
  else if (u < 640) { W = W1; FK = 128; f = (u - 128) >> 4; kb = (u - 128) & 15; base = 131072; }
  else              { W = W2; FK = 128; f = (u - 640) >> 4; kb = (u - 640) & 15; base = 655360; }
  const int t = threadIdx.x;
#pragma unroll
  for (int i = 0; i < 4; ++i) {
    const int e = t + i * 256;  // 0..1023
    const int kk = e >> 7, h = e & 127;
    tile[kk][h] = W[(f * FK + kb * 8 + kk) * 128 + h];
  }
  __syncthreads();
  unsigned short* dst = Wt + base + f * (FK / 8) * 1024 + kb * 1024;
  const int h = t >> 1;
  const int j0 = (t & 1) * 4;
  u16x4 v;
  v.x = f2bf_rne(tile[j0 + 0][h]);
  v.y = f2bf_rne(tile[j0 + 1][h]);
  v.z = f2bf_rne(tile[j0 + 2][h]);
  v.w = f2bf_rne(tile[j0 + 3][h]);
  *(u16x4*)&dst[t * 4] = v;
}

// ---------------- main kernel ----------------
// One "step" = 8 granule loads (16B/lane each) + 16 MFMA.
//   layers 1,2 (KQ=8): step s = field f=s; per-lane granule = s*16 + 2*i+half.
//   layer 0   (KQ=2): step s = fields 4s..4s+3; same granule indices
//     (i = 2*fi+kq), only MFMA pairing + xs handling differ.
// STEPS: 8 (L0) or 32 (L1/L2).
template <int KQ, int STEPS, int LAYER>
DEVINL void run_layer(const unsigned short* __restrict__ WtL,
                      const float* __restrict__ bias,
                      const float* __restrict__ x0g,
                      float* __restrict__ outp, int outoff,
                      unsigned int* SB,
                      int wgb0, int mrow, int npair, int l31, int half) {
  __syncthreads();  // state in SB ready (prologue or previous epilogue)

  // --- B-frags (S) from SB into registers, once per layer ---
  // slot (half,j) of sfr[nt][kq] holds S[r][k = kq*16 + half*8 + j],
  // r = npair*64 + nt*32 + l31. SB row k2=k/2 packs (k even lo16, k odd hi16);
  // addr = k2*128 + r -> bank r%32 = l31, conflict-free.
  int4 sfr[2][KQ];
  const int rb = npair * 64;
#pragma unroll
  for (int nt = 0; nt < 2; ++nt) {
    const int r = rb + nt * 32 + l31;
#pragma unroll
    for (int kq = 0; kq < KQ; ++kq) {
      const int row0 = kq * 8 + half * 4;
      int4 v;
      v.x = (int)SB[(row0 + 0) * 128 + r];
      v.y = (int)SB[(row0 + 1) * 128 + r];
      v.z = (int)SB[(row0 + 2) * 128 + r];
      v.w = (int)SB[(row0 + 3) * 128 + r];
      sfr[nt][kq] = v;
    }
  }
  __syncthreads();  // all waves hold sfr; SB free for this layer's epilogue

  f32x16 zv;
#pragma unroll
  for (int e = 0; e < 16; ++e) zv[e] = 0.f;
  f32x16 outacc[2] = {zv, zv};

  // per-lane W base: granule = step*16 + 2*i + half; elem offset h*8 u16
  const char* gb = (const char*)WtL +
                   (size_t)(half * 2048 + (mrow * 32 + l31) * 16);
  const int xb0 = (wgb0 + npair * 2 + 0) * 1024 + l31;
  const int xb1 = (wgb0 + npair * 2 + 1) * 1024 + l31;

  auto ldw = [&](short8* wv, int s) {
#pragma unroll
    for (int i = 0; i < 8; ++i)
      wv[i] = *(const short8*)(gb + (size_t)s * 32768 + i * 4096);
  };
  auto doF = [&](const short8* wv, float xs0, float xs1) {  // KQ==8
    f32x16 Y0, Y1;
#pragma unroll
    for (int i = 0; i < 8; ++i) {
      const short8 s0 = __builtin_bit_cast(short8, sfr[0][i % KQ]);
      const short8 s1 = __builtin_bit_cast(short8, sfr[1][i % KQ]);
      Y0 = mfma_bf16(wv[i], s0, i == 0 ? zv : Y0);
      Y1 = mfma_bf16(wv[i], s1, i == 0 ? zv : Y1);
    }
#pragma unroll
    for (int e = 0; e < 16; ++e) {
      outacc[0][e] += xs0 * Y0[e];
      outacc[1][e] += xs1 * Y1[e];
    }
  };
  auto doG = [&](const short8* wv, const float (&xs)[2][4]) {  // KQ==2
    const short8 s00 = __builtin_bit_cast(short8, sfr[0][0]);
    const short8 s01 = __builtin_bit_cast(short8, sfr[0][KQ - 1]);
    const short8 s10 = __builtin_bit_cast(short8, sfr[1][0]);
    const short8 s11 = __builtin_bit_cast(short8, sfr[1][KQ - 1]);
#pragma unroll
    for (int fi = 0; fi < 4; ++fi) {
      f32x16 Y0 = mfma_bf16(wv[2 * fi], s00, zv);
      Y0 = mfma_bf16(wv[2 * fi + 1], s01, Y0);
      f32x16 Y1 = mfma_bf16(wv[2 * fi], s10, zv);
      Y1 = mfma_bf16(wv[2 * fi + 1], s11, Y1);
#pragma unroll
      for (int e = 0; e < 16; ++e) {
        outacc[0][e] += xs[0][fi] * Y0[e];
        outacc[1][e] += xs[1][fi] * Y1[e];
      }
    }
  };

  short8 wa[8], wb[8];
  if constexpr (KQ == 8) {
    ldw(wa, 0);
    float xa0 = x0g[xb0], xa1 = x0g[xb1];
#pragma unroll 1
    for (int s2 = 0; s2 < STEPS / 2; ++s2) {
      const int s = 2 * s2;
      ldw(wb, s + 1);  // in flight while doF(wa) runs
      const float xv0 = x0g[xb0 + (s + 1) * 32];
      const float xv1 = x0g[xb1 + (s + 1) * 32];
      doF(wa, xa0, xa1);
      if (s + 2 < STEPS) {
        ldw(wa, s + 2);
        xa0 = x0g[xb0 + (s + 2) * 32];
        xa1 = x0g[xb1 + (s + 2) * 32];
      }
      doF(wb, xv0, xv1);
    }
  } else {
    ldw(wa, 0);
    float xa[2][4], xv[2][4];
#pragma unroll
    for (int fi = 0; fi < 4; ++fi) {
      xa[0][fi] = x0g[xb0 + fi * 32];
      xa[1][fi] = x0g[xb1 + fi * 32];
    }
#pragma unroll 1
    for (int s2 = 0; s2 < STEPS / 2; ++s2) {
      const int s = 2 * s2;
      ldw(wb, s + 1);
#pragma unroll
      for (int fi = 0; fi < 4; ++fi) {
        xv[0][fi] = x0g[xb0 + ((s + 1) * 4 + fi) * 32];
        xv[1][fi] = x0g[xb1 + ((s + 1) * 4 + fi) * 32];
      }
      doG(wa, xa);
      if (s + 2 < STEPS) {
        ldw(wa, s + 2);
#pragma unroll
        for (int fi = 0; fi < 4; ++fi) {
          xa[0][fi] = x0g[xb0 + ((s + 2) * 4 + fi) * 32];
          xa[1][fi] = x0g[xb1 + ((s + 2) * 4 + fi) * 32];
        }
      }
      doG(wb, xv);
    }
  }

  // --- epilogue ---
  // C/D layout: col = lane&31 = n (r within 32-block);
  //             row = (reg&3)+8*(reg>>2)+4*half = h within 32-block.
  float bv[16];
#pragma unroll
  for (int e = 0; e < 16; ++e)
    bv[e] = bias[mrow * 32 + (e & 3) + 8 * (e >> 2) + 4 * half];

  if constexpr (LAYER < 2) {
    // next state S'[r][h] = bf16(acc+bias), packed [h/2][r] u32 into SB
#pragma unroll
    for (int nt = 0; nt < 2; ++nt) {
      const int r = rb + nt * 32 + l31;
#pragma unroll
      for (int g = 0; g < 4; ++g) {
        const int h2 = mrow * 16 + 4 * g + 2 * half;
        const float v0 = outacc[nt][4 * g + 0] + bv[4 * g + 0];
        const float v1 = outacc[nt][4 * g + 1] + bv[4 * g + 1];
        const float v2 = outacc[nt][4 * g + 2] + bv[4 * g + 2];
        const float v3 = outacc[nt][4 * g + 3] + bv[4 * g + 3];
        SB[h2 * 128 + r] =
            (unsigned)f2bf_rne(v0) | ((unsigned)f2bf_rne(v1) << 16);
        SB[(h2 + 1) * 128 + r] =
            (unsigned)f2bf_rne(v2) | ((unsigned)f2bf_rne(v3) << 16);
      }
    }
  }

  // final output: out[b, outoff+h] = sum_d acc + 32*bias (d = l31 lanes)
#pragma unroll
  for (int nt = 0; nt < 2; ++nt) {
    float sv[16];
#pragma unroll
    for (int e = 0; e < 16; ++e) {
      float v = outacc[nt][e];
      v += __shfl_xor(v, 1);
      v += __shfl_xor(v, 2);
      v += __shfl_xor(v, 4);
      v += __shfl_xor(v, 8);
      v += __shfl_xor(v, 16);
      sv[e] = v + 32.0f * bv[e];
    }
    if (l31 == 0) {
      const int b = npair * 2 + nt;
#pragma unroll
      for (int g = 0; g < 4; ++g) {
        const int h = mrow * 32 + 8 * g + 4 * half;
        float4 o = {sv[4 * g + 0], sv[4 * g + 1], sv[4 * g + 2], sv[4 * g + 3]};
        *(float4*)&outp[b * 384 + outoff + h] = o;
      }
    }
  }
}

__global__ __launch_bounds__(512, 2) void cin_kernel(
    const float* __restrict__ x0g, const unsigned short* __restrict__ Wt,
    const float* __restrict__ b0, const float* __restrict__ b1,
    const float* __restrict__ b2, float* __restrict__ out) {
  __shared__ unsigned int SB[64 * 128];  // 32KB state only — no W staging

  const int t = threadIdx.x;
  const int lane = t & 63;
  const int w = t >> 6;      // 0..7
  const int mrow = w & 3;    // h-tile of 32
  const int npair = w >> 2;  // batch pair (2 batches each)
  const int l31 = lane & 31, half = lane >> 5;
  const int wgb0 = blockIdx.x * 4;  // 4 batches per WG

  // prologue: S1 = bf16(x0^T) -> SB ([g/2][r] u32, r = b_local*32+d)
#pragma unroll
  for (int s = 0; s < 4; ++s) {
    const int i = t + s * 512;  // 0..2047
    const int r = i & 127, g2 = i >> 7;
    const float* p = &x0g[(wgb0 + (r >> 5)) * 1024 + (2 * g2) * 32 + (r & 31)];
    SB[g2 * 128 + r] =
        (unsigned)f2bf_rne(p[0]) | ((unsigned)f2bf_rne(p[32]) << 16);
  }
  // ordering handled by the entry barrier in run_layer

  float* outp = out + (size_t)wgb0 * 384;
  run_layer<2, 8, 0>(Wt, b0, x0g, outp, 0, SB, wgb0, mrow, npair, l31, half);
  run_layer<8, 32, 1>(Wt + 131072, b1, x0g, outp, 128, SB,
                      wgb0, mrow, npair, l31, half);
  run_layer<8, 32, 2>(Wt + 655360, b2, x0g, outp, 256, SB,
                      wgb0, mrow, npair, l31, half);
}

extern "C" void kernel_launch(void* const* d_in, const int* in_sizes, int n_in,
                              void* d_out, int out_size, void* d_ws, size_t ws_size,
                              hipStream_t stream) {
  (void)in_sizes; (void)n_in; (void)out_size; (void)ws_size;
  const float* x0 = (const float*)d_in[0];
  const float* W0 = (const float*)d_in[1];
  const float* W1 = (const float*)d_in[2];
  const float* W2 = (const float*)d_in[3];
  const float* b0 = (const float*)d_in[4];
  const float* b1 = (const float*)d_in[5];
  const float* b2 = (const float*)d_in[6];
  unsigned short* Wt = (unsigned short*)d_ws;  // 2,359,296 B

  pack_w_kernel<<<1152, 256, 0, stream>>>(W0, W1, W2, Wt);
  // 256 WGs x 512 thr = 1 WG/CU (8 waves, 2/SIMD), barrierless K-loop
  cin_kernel<<<256, 512, 0, stream>>>(x0, Wt, b0, b1, b2, (float*)d_out);
}